// Round 7
// baseline (250.585 us; speedup 1.0000x reference)
//
#include <hip/hip_runtime.h>
#include <hip/hip_bf16.h>

// MultiHeadAttentionClassical: B=2, S=2048, E=1024, H=16, DK=64
// Established: float inputs fp32, out fp32; bf16 internal compute.
// R18: attn ported to the m214-style 32x32 structure:
//  - 4 waves x 32 q-rows (q-block 128, grid 512 = 2 blocks/CU).
//  - QK^T = mfma_32x32x16(K,Q): lane holds col q=l&31, rows = 16 keys.
//  - P stays IN REGISTER: exp2 -> v_cvt_pk_bf16_f32 pairs -> 4x
//    v_permlane32_swap_b32 per 32 keys redistributes straight into the PV
//    A-fragment layout (T12). lds_p and its write/wait/read chain deleted.
//  - mask: byte AND-mask on packed words post-swap (Mp repacked, same 8MB).
//  - lsum via ones-MFMA (row layout matches o
//  - LDS 51.2 -> 32 KB (K/V dbuf only).
// R17 post-mortem: cvt_pk/mask-load null (m240: compiler already good);
// occupancy/LDS-traffic probes null => structural port, not peephole.

typedef __attribute__((ext_vector_type(8))) short short8;
typedef __attribute__((ext_vector_type(4))) float f32x4;
typedef __attribute__((ext_vector_type(16))) float f32x16;

#define MFMA16(a, b, c) __builtin_amdgcn_mfma_f32_16x16x32_bf16(a, b, c, 0, 0, 0)
#define MFMA32(a, b, c) __builtin_amdgcn_mfma_f32_32x32x16_bf16(a, b, c, 0, 0, 0)

#define BATCH 2
#define SEQ   2048
#define EMB   1024
#define HEADS 16
#define DKK   64

typedef __hip_bfloat16 bf16;

static __device__ __forceinline__ short bf16b(float f) {
    union { bf16 h; short s; } u;
    u.h = __float2bfloat16(f);
    return u.s;
}
static __device__ __forceinline__ unsigned cvtpk(float lo, float hi) {
    unsigned r;
    asm("v_cvt_pk_bf16_f32 %0, %1, %2" : "=v"(r) : "v"(lo), "v"(hi));
    return r;
}
static __device__ __forceinline__ void swap32(unsigned &a, unsigned &b) {
    asm("v_permlane32_swap_b32 %0, %1" : "+v"(a), "+v"(b));
}
static __device__ __forceinline__ short8 ld8k(const bf16* p) {
    return *(const short8*)p;
}
static __device__ __forceinline__ short8 ld8kf(const float* p) {
    const f32x4 a = *(const f32x4*)p;
    const f32x4 b = *(const f32x4*)(p + 4);
    short8 r;
    r[0] = bf16b(a[0]); r[1] = bf16b(a[1]); r[2] = bf16b(a[2]); r[3] = bf16b(a[3]);
    r[4] = bf16b(b[0]); r[5] = bf16b(b[1]); r[6] = bf16b(b[2]); r[7] = bf16b(b[3]);
    return r;
}

// async global->LDS, 16B/lane (LDS dest = wave-uniform base + lane*16)
static __device__ __forceinline__ void glds16(const bf16* g, bf16* l) {
    __builtin_amdgcn_global_load_lds(
        (const __attribute__((address_space(1))) void*)g,
        (__attribute__((address_space(3))) void*)l, 16, 0, 0);
}

// ---------------------------------------------------------------------------
// flags[1]=1 -> byte mask, 0 -> int32 mask.
__global__ void detect_kernel(const unsigned int* __restrict__ mw,
                              int* __restrict__ flags) {
    __shared__ int mbyte;
    if (threadIdx.x == 0) mbyte = 0;
    __syncthreads();
    int mb = 0;
    for (int i = threadIdx.x; i < 4096; i += 256)
        if (mw[i] > 1u) mb = 1;
    if (mb) atomicOr(&mbyte, 1);
    __syncthreads();
    if (threadIdx.x == 0) { flags[0] = 1; flags[1] = mbyte; }
}

// ---------------------------------------------------------------------------
// Byte AND-mask Mp (8MB) in the R18 attn lane order.
//   group g = ((b*32+it)*16+qb)*4 + wv;  per lane 8 u32 at Mp[g*512+lane*8]:
//   word k = kb*4 + t*2 + u covers keys it*64 + kb*32 + t*16 + hi*8 + u*4+{0..3}
//   for q = qb*128 + wv*32 + (lane&31), hi = lane>>5.
//   byte r = 0xFF if mask[b][q][key] == 0 (keep), else 0x00.
__global__ __launch_bounds__(256) void pack_mask(
        const void* __restrict__ mp, unsigned* __restrict__ Mp,
        const int* __restrict__ flags) {
    const bool m8 = flags[1] != 0;
    const int T = blockIdx.x * 256 + threadIdx.x;   // 262144 threads
    const int lane = T & 63, g = T >> 6;            // g in [0, 4096)
    const int wvv = g & 3;
    const int qb  = (g >> 2) & 15;
    const int it  = (g >> 6) & 31;
    const int b   = g >> 11;
    const int l32 = lane & 31, hi = lane >> 5;
    const int q = qb * 128 + wvv * 32 + l32;
    const size_t rowb = ((size_t)(b * 2048 + q)) * 2048;

    unsigned out[8];
    if (m8) {
        const unsigned char* p8 = (const unsigned char*)mp;
#pragma unroll
        for (int k = 0; k < 8; ++k) {
            const int kb = k >> 2, tt = (k >> 1) & 1, u = k & 1;
            const int key0 = it * 64 + kb * 32 + tt * 16 + hi * 8 + u * 4;
            const unsigned v = *(const unsigned*)(p8 + rowb + key0);
            unsigned w = 0;
#pragma unroll
            for (int r = 0; r < 4; ++r)
                w |= ((((v >> (8 * r)) & 0xFFu) == 0u) ? 0xFFu : 0u) << (8 * r);
            out[k] = w;
        }
    } else {
        const int* p32 = (const int*)mp;
#pragma unroll
        for (int k = 0; k < 8; ++k) {
            const int kb = k >> 2, tt = (k >> 1) & 1, u = k & 1;
            const int key0 = it * 64 + kb * 32 + tt * 16 + hi * 8 + u * 4;
            const int4 v = *(const int4*)(p32 + rowb + key0);
            unsigned w = 0;
            w |=  (v.x == 0) ? 0xFFu : 0u;
            w |= ((v.y == 0) ? 0xFFu : 0u) << 8;
            w |= ((v.z == 0) ? 0xFFu : 0u) << 16;
            w |= ((v.w == 0) ? 0xFFu : 0u) << 24;
            out[k] = w;
        }
    }
    unsigned* dst = Mp + (size_t)g * 512 + lane * 8;
    *(uint4*)dst       = make_uint4(out[0], out[1], out[2], out[3]);
    *(uint4*)(dst + 4) = make_uint4(out[4], out[5], out[6], out[7]);
}

// ---------------------------------------------------------------------------
// Fused fp32->bf16 conversion of x, Wq, Wk, Wv, Wo.
__global__ __launch_bounds__(256) void cvt_all(
        const float* __restrict__ x,  const float* __restrict__ wq,
        const float* __restrict__ wk, const float* __restrict__ wv,
        const float* __restrict__ wo,
        bf16* __restrict__ xb,  bf16* __restrict__ wqb,
        bf16* __restrict__ wkb, bf16* __restrict__ wvb,
        bf16* __restrict__ wob) {
    const int bid = blockIdx.x;
    const float* s; bf16* d; int base;
    if (bid < 2048)      { s = x;  d = xb;  base = bid; }
    else if (bid < 2560) { s = wq; d = wqb; base = bid - 2048; }
    else if (bid < 3072) { s = wk; d = wkb; base = bid - 2560; }
    else if (bid < 3584) { s = wv; d = wvb; base = bid - 3072; }
    else                 { s = wo; d = wob; base = bid - 3584; }
    const int i = (base * 256 + threadIdx.x) * 8;
    *(short8*)(d + i) = ld8kf(s + i);
}

// ---------------------------------------------------------------------------
// Staged QKV GEMM: C[4096,3072] = X @ [Wq;Wk;Wv]^T + b. 128x128 tile, BK=32,
// 1-barrier double-buffered staging. Q,K -> [b,h,s,d]; V -> [b,h,d,s].
// Q (sel==0) is pre-scaled by 0.125/ln2 so attn can use raw exp2.
__global__ __launch_bounds__(256) void gemm_qkv_staged(
        const bf16* __restrict__ X,
        const bf16* __restrict__ Wq, const bf16* __restrict__ Wk,
        const bf16* __restrict__ Wv,
        const float* __restrict__ bq, const float* __restrict__ bk,
        const float* __restrict__ bv,
        bf16* __restrict__ qo, bf16* __restrict__ ko, bf16* __restrict__ vo) {
    __shared__ bf16 As[2][128 * 32];   // 2 x 8 KB
    __shared__ bf16 Bs[2][128 * 32];   // 2 x 8 KB

    const int t = threadIdx.x, lane = t & 63;
    const int wv = t >> 6;
    const int mb = blockIdx.x / 24, nb = blockIdx.x % 24;
    const int m0 = mb * 128;
    const int n0g = nb * 128;
    const int sel = n0g >> 10;          // 0=Q 1=K 2=V
    const int n0 = n0g & 1023;
    const bf16* W     = sel == 0 ? Wq : (sel == 1 ? Wk : Wv);
    const float* bias = sel == 0 ? bq : (sel == 1 ? bk : bv);
    bf16* out         = sel == 0 ? qo : (sel == 1 ? ko : vo);
    const float oscale = sel == 0 ? 0.18033688011f : 1.0f;   // 0.125/ln2

    const int wr = wv >> 1, wc = wv & 1;
    const int m_off = wr * 64, n_off = wc * 64;
    const int l16 = lane & 15, quad = lane >> 4;

    int srow[2], sg[2];
#pragma unroll
    for (int i = 0; i < 2; ++i) {
        const int c = i * 256 + t;
        srow[i] = c >> 2;
        sg[i]   = (c & 3) ^ (srow[i] & 3);
    }

    f32x4 acc[4][4];
#pragma unroll
    for (int i = 0; i < 4; ++i)
#pragma unroll
        for (int j = 0; j < 4; ++j)
            acc[i][j] = (f32x4){0.f, 0.f, 0.f, 0.f};

    // prologue: stage tile 0 into buf 0
#pragma unroll
    for (int i = 0; i < 2; ++i) {
        glds16(X + (m0 + srow[i]) * 1024 + sg[i] * 8, &As[0][(i * 256 + t) * 8]);
        glds16(W + (n0 + srow[i]) * 1024 + sg[i] * 8, &Bs[0][(i * 256 + t) * 8]);
    }

    for (int it = 0; it < 32; ++it) {
        __syncthreads();
        if (it < 31) {
            const int ktn = (it + 1) * 32;
            const int nb_ = (it + 1) & 1;
#pragma unroll
            for (int i = 0; i < 2; ++i) {
                glds16(X + (m0 + srow[i]) * 1024 + ktn + sg[i] * 8,
                       &As[nb_][(i * 256 + t) * 8]);
                glds16(W + (n0 + srow[i]) * 1024 + ktn + sg[i] * 8,
                       &Bs[nb_][(i * 256 + t) * 8]);
            }
        }
        const bf16* Ab = As[it & 1];
        const bf16* Bb = Bs[it & 1];
        short8 af[4], bfr[4];
#pragma unroll
        for (int ii = 0; ii < 4; ++ii) {
            const int row = m_off + ii * 16 + l16;
            const int slot = quad ^ (row & 3);
            af[ii] = *(const short8*)(Ab + row * 32 + slot * 8);
        }
#pragma unroll
        for (int jj = 0; jj < 4; ++jj) {
            const int row = n_off + jj * 16 + l16;
            const int slot = quad ^ (row & 3);
            bfr[jj] = *(const short8*)(Bb + row * 32 + slot * 8);
        }
#pragma unroll
        for (int ii = 0; ii < 4; ++ii)
#pragma unroll
            for (int jj = 0; jj < 4; ++jj)
                acc[ii][jj] = MFMA16(af[ii], bfr[jj], acc[ii][jj]);
    }

#pragma unroll
    for (int j = 0; j < 4; ++j) {
        const int nl = n0 + n_off + j * 16 + l16;
        const float bj = bias[nl];
        const int h = nl >> 6, d = nl & 63;
#pragma unroll
        for (int i = 0; i < 4; ++i) {
#pragma unroll
            for (int r = 0; r < 4; ++r) {
                const int m = m0 + m_off + i * 16 + quad * 4 + r;
                const float v = (acc[i][j][r] + bj) * oscale;
                const int bb = m >> 11, ss = m & 2047;
                const int idx = (sel == 2)
                    ? ((bb * HEADS + h) * DKK + d) * SEQ + ss
                    : ((bb * HEADS + h) * SEQ + ss) * DKK + d;
                out[idx] = __float2bfloat16(v);
            }
        }
    }
}

// ---------------------------------------------------------------------------
// Staged output GEMM: C[4096,1024] = X @ Wo^T + bo (fp32 out). 128x64 tile,
// BK=32, 1-barrier double-buffered -> 512 blocks (2/CU).
__global__ __launch_bounds__(256) void gemm_out_staged(
        const bf16* __restrict__ X,
        const bf16* __restrict__ W, const float* __restrict__ bias,
        float* __restrict__ out) {
    __shared__ bf16 As[2][128 * 32];   // 2 x 8 KB
    __shared__ bf16 Bs[2][64 * 32];    // 2 x 4 KB

    const int t = threadIdx.x, lane = t & 63;
    const int wv = t >> 6;
    const int mb = blockIdx.x >> 4, nb = blockIdx.x & 15;
    const int m0 = mb * 128, n0 = nb * 64;
    const int wr = wv >> 1, wc = wv & 1;
    const int m_off = wr * 64, n_off = wc * 32;
    const int l16 = lane & 15, quad = lane >> 4;

    int srow[2], sg[2];
#pragma unroll
    for (int i = 0; i < 2; ++i) {
        const int c = i * 256 + t;
        srow[i] = c >> 2;
        sg[i]   = (c & 3) ^ (srow[i] & 3);
    }
    const int brow = t >> 2;
    const int bslot = (t & 3) ^ (brow & 3);

    f32x4 acc[4][2];
#pragma unroll
    for (int i = 0; i < 4; ++i)
#pragma unroll
        for (int j = 0; j < 2; ++j)
            acc[i][j] = (f32x4){0.f, 0.f, 0.f, 0.f};

#pragma unroll
    for (int i = 0; i < 2; ++i)
        glds16(X + (m0 + srow[i]) * 1024 + sg[i] * 8, &As[0][(i * 256 + t) * 8]);
    glds16(W + (n0 + brow) * 1024 + bslot * 8, &Bs[0][t * 8]);

    for (int it = 0; it < 32; ++it) {
        __syncthreads();
        if (it < 31) {
            const int ktn = (it + 1) * 32;
            const int nb_ = (it + 1) & 1;
#pragma unroll
            for (int i = 0; i < 2; ++i)
                glds16(X + (m0 + srow[i]) * 1024 + ktn + sg[i] * 8,
                       &As[nb_][(i * 256 + t) * 8]);
            glds16(W + (n0 + brow) * 1024 + ktn + bslot * 8, &Bs[nb_][t * 8]);
        }
        const bf16* Ab = As[it & 1];
        const bf16* Bb = Bs[it & 1];
        short8 af[4], bfr[2];
#pragma unroll
        for (int ii = 0; ii < 4; ++ii) {
            const int row = m_off + ii * 16 + l16;
            const int slot = quad ^ (row & 3);
            af[ii] = *(const short8*)(Ab + row * 32 + slot * 8);
        }
#pragma unroll
        for (int jj = 0; jj < 2; ++jj) {
            const int row = n_off + jj * 16 + l16;
            const int slot = quad ^ (row & 3);
            bfr[jj] = *(const short8*)(Bb + row * 32 + slot * 8);
        }
#pragma unroll
        for (int ii = 0; ii < 4; ++ii)
#pragma unroll
            for (int jj = 0; jj < 2; ++jj)
                acc[ii][jj] = MFMA16(af[ii], bfr[jj], acc[ii][jj]);
    }

#pragma unroll
    for (int j = 0; j < 2; ++j) {
        const int n = n0 + n_off + j * 16 + l16;
        const float bj = bias[n];
#pragma unroll
        for (int i = 0; i < 4; ++i) {
#pragma unroll
            for (int r = 0; r < 4; ++r) {
                const int m = m0 + m_off + i * 16 + quad * 4 + r;
                out[m * 1024 + n] = acc[i][j][r] + bj;
            }
        }
    }
}

// ---------------------------------------------------------------------------
// Flash attention, 32x32-MFMA in-register-P structure (m214-style):
// block = 128 q-rows x one (b,h); 4 waves x 32 q-rows; grid 512 = 2/CU.
// QK^T swapped (A=K, B=Q), mfma_32x32x16: lane -> col q = l&31,
// rows = 16 keys at (reg&3)+8*(reg>>2)+4*hi. exp2 in-register, cvt_pk pairs,
// permlane32_swap redistributes P straight into the PV A-fragment layout
// (keys (l>>5)*8+e per k-slice) -- P never touches LDS.
// Mask: byte AND-mask words post-swap. lsum: ones-MFMA (row layout = o).
__global__ __launch_bounds__(256, 2) void attn_kernel(
        const bf16* __restrict__ Qw,
        const bf16* __restrict__ Kw,
        const bf16* __restrict__ Vw,
        const unsigned* __restrict__ Mp,
        bf16* __restrict__ attn_out) {
    const int t = threadIdx.x;
    const int lane = t & 63;
    const int wv   = t >> 6;                // 0..3
    const int l32 = lane & 31, hi = lane >> 5;
    const int h = blockIdx.y, b = blockIdx.z;
    const int bh = b * HEADS + h;
    const int qb = blockIdx.x;              // 0..15
    const int qb0 = qb * 128;

    const bf16* Q  = Qw + bh * SEQ * DKK;
    const bf16* Kp = Kw + bh * SEQ * DKK;
    const bf16* Vt = Vw + bh * DKK * SEQ;

    __shared__ bf16 Ks[2][4096];   // [buf][key*64 + slot*8], slot = s ^ (key&7)
    __shared__ bf16 Vs[2][4096];   // [buf][d*64   + slot*8], slot = s ^ (d&7)

    // Q B-fragments (col q = l32): k-slice ks -> d = ks*16 + hi*8 + e
    short8 qf[4];
#pragma unroll
    for (int ks = 0; ks < 4; ++ks)
        qf[ks] = ld8k(Q + (qb0 + wv * 32 + l32) * DKK + ks * 16 + hi * 8);

    const short ob = bf16b(1.0f);
    short8 ones;
#pragma unroll
    for (int e = 0; e < 8; ++e) ones[e] = ob;

    f32x16 oA = {}, oB = {}, lacc = {};
    const f32x16 z16 = {};

    // staging: two 16B glds16 per thread per array (8KB tiles)
    int srow[2], sg[2];
#pragma unroll
    for (int i = 0; i < 2; ++i) {
        const int c = i * 256 + t;
        srow[i] = c >> 3;
        sg[i]   = (c & 7) ^ (srow[i] & 7);
    }
#pragma unroll
    for (int i = 0; i < 2; ++i)
        glds16(Kp + srow[i] * DKK + sg[i] * 8, &Ks[0][(i * 256 + t) * 8]);
#pragma unroll
    for (int i = 0; i < 2; ++i)
        glds16(Vt + srow[i] * SEQ + sg[i] * 8, &Vs[0][(i * 256 + t) * 8]);

    // mask: 8 u32/lane/iter, group = ((b*32+it)*16+qb)*4 + wv
    const unsigned* mp_it =
        Mp + ((size_t)((b * 32) * 16 + qb) * 4 + wv) * 512 + lane * 8;

    for (int it = 0; it < 32; ++it) {
        __syncthreads();
        if (it < 31) {
            const int nb_ = (it + 1) & 1;
            const int ktn = (it + 1) * 64;
#pragma unroll
            for (int i = 0; i < 2; ++i)
                glds16(Kp + (ktn + srow[i]) * DKK + sg[i] * 8,
                       &Ks[nb_][(i * 256 + t) * 8]);
#pragma unroll
            for (int i = 0; i < 2; ++i)
                glds16(Vt + srow[i] * SEQ + ktn + sg[i] * 8,
                       &Vs[nb_][(i * 256 + t) * 8]);
        }
        const uint4 mA = *(const uint4*)mp_it;
        const uint4 mB = *(const uint4*)(mp_it + 4);
        mp_it += 32768;

        const bf16* Kb = Ks[it & 1];
        const bf16* Vb = Vs[it & 1];

        // K A-fragments: rows = keys kb*32 + l32; k(d) = ks*16 + hi*8 + e
        short8 kf0[4], kf1[4];
#pragma unroll
        for (int ks = 0; ks < 4; ++ks) {
            const int sl = (((ks * 2 + hi) ^ (l32 & 7))) * 8;
            kf0[ks] = *(const short8*)(Kb + l32 * 64 + sl);
            kf1[ks] = *(const short8*)(Kb + (32 + l32) * 64 + sl);
        }

        f32x16 s0, s1;
        __builtin_amdgcn_s_setprio(1);
        s0 = MFMA32(kf0[0], qf[0], z16);
        s0 = MFMA32(kf0[1], qf[1], s0);
        s0 = MFMA32(kf0[2], qf[2], s0);
        s0 = MFMA32(kf0[3], qf[3], s0);
        s1 = MFMA32(kf1[0], qf[0], z16);
        s1 = MFMA32(kf1[1], qf[1], s1);
        s1 = MFMA32(kf1[2], qf[2], s1);
        s1 = MFMA32(kf1[3], qf[3], s1);
        __builtin_amdgcn_s_setprio(0);

        // ---- key-block 0 (keys 0..31): softmax in-register + PV ----
        {
            unsigned c0 = cvtpk(__builtin_exp2f(s0[0]),  __builtin_exp2f(s0[1]));
            unsigned c1 = cvtpk(__builtin_exp2f(s0[2]),  __builtin_exp2f(s0[3]));
            unsigned c2 = cvtpk(__builtin_exp2f(s0[4]),  __builtin_exp2f(s0[5]));
            unsigned c3 = cvtpk(__builtin_exp2f(s0[6]),  __builtin_exp2f(s0[7]));
            unsigned c4 = cvtpk(__builtin_exp2f(s0[8]),  __builtin_exp2f(s0[9]));
            unsigned c5 = cvtpk(__builtin_exp2f(s0[10]), __builtin_exp2f(s0[11]));
            unsigned c6 = cvtpk(__builtin_exp2f(s0[12]), __builtin_exp2f(s0[13]));
            unsigned c7 = cvtpk(__builtin_exp2f(s0[14]), __builtin_exp2f(s0[15]));
            swap32(c0, c2); swap32(c1, c3); swap32(c4, c6); swap32(c5, c7);
            union { short8 v; unsigned w[4]; } p0, p1;
            p0.w[0] = c0 & __builtin_amdgcn_perm(0u, mA.x, 0x01010000u);
            p0.w[1] = c1 & __builtin_amdgcn_perm(0u, mA.x, 0x03030202u);
            p0.w[2] = c2 & __builtin_amdgcn_perm(0u, mA.y, 0x01010000u);
            p0.w[3] = c3 & __builtin_amdgcn_perm(0u, mA.y, 0x03030202u);
            p1.w[0] = c4 & __builtin_amdgcn_perm(0u, mA.z, 0x01010000u);
            p1.w[1] = c5 & __builtin_amdgcn_perm(0u, mA.z, 0x03030202u);
            p1.w[2] = c6 & __builtin_amdgcn_perm(0u, mA.w, 0x01010000u);
            p1.w[3] = c7 & __builtin_amdgcn_perm(0u, mA.w, 0x03030202u);

            const int sl0 = ((0 + hi) ^ (l32 & 7)) * 8;   // kb=0, t=0
            const int sl1 = ((2 + hi) ^ (l32 & 7)) * 8;   // kb=0, t=1
            const short8 vf00 = *(const short8*)(Vb + l32 * 64 + sl0);
            const short8 vf10 = *(const short8*)(Vb + (32 + l32) * 64 + sl0);
            const short8 vf01 = *(const short8*)(Vb + l32 * 64 + sl1);
            const short8 vf11 = *(const short8*)(Vb + (32 + l32) * 64 + sl1);
            __builtin_amdgcn_s_setprio(1);
            lacc = MFMA32(p0.v, ones, lacc);
            oA = MFMA32(p0.v, vf00, oA);
            oB = MFMA32(p0.v, vf10, oB);
            lacc = MFMA32(p1.v, ones, lacc);
            oA = MFMA32(p1.v, vf01, oA);
            oB = MFMA32(p1.v, vf11, oB);
            __builtin_amdgcn_s_setprio(0);
        }
        // ---- key-block 1 (keys 32..63) ----
        {
            unsigned c0 = cvtpk(__builtin_exp2f(s1[0]),  __builtin_exp2f(s1[1]));
            unsigned c1 = cvtpk(__builtin_exp2f(s1[2]),  __builtin_exp2f(s1[3]));
            unsigned c2 = cvtpk(__builtin_exp2f(s1[4]),  __builtin_exp2f(s1[5]));
            unsigned c3 = cvtpk(__builtin_exp2f(s1[6]),  __builtin_exp2f(s1[7]));
            unsigned c4 = cvtpk(__builtin_exp2f(s1[8]),  __builtin_exp2f(s1[9]));
            unsigned c5 = cvtpk(__builtin_exp2f(s1[10]), __builtin_exp2f(s1[11]));
            unsigned c6 = cvtpk(__builtin_exp2f(s1[12]), __builtin_exp2f(s1[13]));
            unsigned c7 = cvtpk(__builtin_exp2f(s1[14]), __builtin_exp2f(s1[15]));
            swap32(c0, c2); swap32(c1, c3); swap32(c4, c6); swap32(c5, c7);
            union { short8 v; unsigned w[4]; } p0, p1;
            p0.w[0] = c0 & __builtin_amdgcn_perm(0u, mB.x, 0x01010000u);
            p0.w[1] = c1 & __builtin_amdgcn_perm(0u, mB.x, 0x03030202u);
            p0.w[2] = c2 & __builtin_amdgcn_perm(0u, mB.y, 0x01010000u);
            p0.w[3] = c3 & __builtin_amdgcn_perm(0u, mB.y, 0x03030202u);
            p1.w[0] = c4 & __builtin_amdgcn_perm(0u, mB.z, 0x01010000u);
            p1.w[1] = c5 & __builtin_amdgcn_perm(0u, mB.z, 0x03030202u);
            p1.w[2] = c6 & __builtin_amdgcn_perm(0u, mB.w, 0x01010000u);
            p1.w[3] = c7 & __builtin_amdgcn_perm(0u, mB.w, 0x03030202u);

            const int sl0 = ((4 + hi) ^ (l32 & 7)) * 8;   // kb=1, t=0
            const int sl1 = ((6 + hi) ^ (l32 & 7)) * 8;   // kb=1, t=1
            const short8 vf00 = *(const short8*)(Vb + l32 * 64 + sl0);
            const short8 vf10 = *(const short8*)(Vb + (32 + l32) * 64 + sl0);
            const short8 vf01 = *(const short8*)(Vb + l32 * 64 + sl1);
            const short8 vf11 = *(const short8*)(Vb + (32 + l32) * 64 + sl1);
            __builtin_amdgcn_s_setprio(1);
            lacc = MFMA32(p0.v, ones, lacc);
            oA = MFMA32(p0.v, vf00, oA);
            oB = MFMA32(p0.v, vf10, oB);
            lacc = MFMA32(p1.v, ones, lacc);
            oA = MFMA32(p1.v, vf01, oA);
            oB = MFMA32(p1.v, vf11, oB);
            __builtin_amdgcn_s_setprio(0);
        }
    }

    // epilogue: lacc[r] = lsum for q-row (r&3)+8*(r>>2)+4*hi (same as o rows)
#pragma unroll
    for (int r = 0; r < 16; ++r) {
        const int qrow = (r & 3) + 8 * (r >> 2) + 4 * hi;
        const float inv = 1.0f / lacc[r];
        const int q = qb0 + wv * 32 + qrow;
        bf16* orow = attn_out + (b * SEQ + q) * EMB + h * DKK;
        orow[l32]      = __float2bfloat16(oA[r] * inv);
        orow[32 + l32] = __float2bfloat16(oB[r] * inv);
    }
}

// ---------------------------------------------------------------------------
extern "C" void kernel_launch(void* const* d_in, const int* in_sizes, int n_in,
                              void* d_out, int out_size, void* d_ws, size_t ws_size,
                              hipStream_t stream) {
    char* ws = (char*)d_ws;
    const size_t MB = 1024 * 1024;
    int*      flags = (int*)ws;
    bf16*     wob   = (bf16*)(ws + 256);                 // [cvt -> out], 2MB
    bf16*     wqb   = (bf16*)(ws + 256 + 2 * MB);        // [cvt -> qkv]
    bf16*     wkb   = (bf16*)(ws + 256 + 4 * MB);
    bf16*     wvb   = (bf16*)(ws + 256 + 6 * MB);
    unsigned* Mp    = (unsigned*)(ws + 256 + 2 * MB);    // [pack -> attn], 8MB,
                                                         // aliases wqb..wvb+pad
    bf16*     xb    = (bf16*)(ws + 256 + 10 * MB);       // [cvt -> qkv], 8MB
    bf16*     k_ws  = (bf16*)(ws + 256 + 18 * MB);       // [qkv -> attn], 8MB
    bf16*     attn_ws = xb;                              // xb dead after QKV

    bf16* q_ws = (bf16*)d_out;
    bf16* v_ws = (bf16*)d_out + 4194304;

    detect_kernel<<<1, 256, 0, stream>>>((const unsigned int*)d_in[1], flags);

    cvt_all<<<4096, 256, 0, stream>>>(
        (const float*)d_in[0], (const float*)d_in[2], (const float*)d_in[4],
        (const float*)d_in[6], (const float*)d_in[8],
        xb, wqb, wkb, wvb, wob);

    gemm_qkv_staged<<<768, 256, 0, stream>>>(
        xb, wqb, wkb, wvb,
        (const float*)d_in[3], (const float*)d_in[5], (const float*)d_in[7],
        q_ws, k_ws, v_ws);

    // after qkv: wqb/wkb/wvb dead -> Mp may alias them
    pack_mask<<<1024, 256, 0, stream>>>(d_in[1], Mp, flags);

    attn_kernel<<<dim3(SEQ / 128, HEADS, BATCH), 256, 0, stream>>>(
        q_ws, k_ws, v_ws, Mp, attn_ws);

    gemm_out_staged<<<512, 256, 0, stream>>>(
        attn_ws, wob, (const float*)d_in[9], (float*)d_out);
}